// Round 15
// baseline (17380.174 us; speedup 1.0000x reference)
//
#include <hip/hip_runtime.h>

#define DK 1024
#define NB 32768
#define BM 128
#define BN 128
#define BKT 32
#define NKT (DK / BKT)     // 32 k-tiles
#define FLUSH_KT 15        // KC=512 panel boundary (after kt 15)

typedef const __attribute__((address_space(1))) void GAS;
typedef __attribute__((address_space(3))) void LAS;

__device__ __forceinline__ void gll16(const void* g, void* l) {
    __builtin_amdgcn_global_load_lds((GAS*)g, (LAS*)l, 16, 0, 0);
}

// Reference model (probes r4-r8, verified r9-r14): np ref = f32 sgemm, KC=512
// K-panels; per element ascending-k single-accumulator f32 FMA chain per
// panel; panel sums added in order (P0 + P1). DO NOT reorder the chain.
// P0 parked in `out` at kt==FLUSH_KT, re-read in epilogue (same thread).
//
// r15: VGPR diet for 4 waves/SIMD (r14 was 176 VGPR -> 2 waves/SIMD, latency
// exposed). Only ONE operand array lives across a c-granule:
//   NT modes: b4[8] resident (32 VGPR), A streamed one float4 at a time.
//   NN mode1: a4[8] resident, B streamed two float4 per e.
// Live ~115 regs; amdgpu_waves_per_eu(4) caps at 128 (r11 lesson: only safe
// because the live set genuinely fits).
// MODE 0: y = x @ Pi^T (NT B) -> idx to out, yhat=cent[idx] to yout
// MODE 1: xhat = yhat @ Pi (NN B) -> resid = x - xhat to out
// MODE 2: p = resid @ S^T (NT B) -> sign to out
template<int MODE>
__global__ __launch_bounds__(256)
__attribute__((amdgpu_waves_per_eu(4)))
void gk(const float* __restrict__ A,
        const float* __restrict__ W,
        const float* __restrict__ X,
        const float* __restrict__ cent,
        const float* __restrict__ bnd,
        float* __restrict__ out,
        float* __restrict__ yout)
{
    __shared__ float Bs[2][BN * BKT];
    __shared__ float centS[8];

    const int tid  = threadIdx.x;
    const int lane = tid & 63;
    const int wid  = tid >> 6;
    const int tx8 = tid & 15, ty8 = tid >> 4;
    const int m0 = blockIdx.y * BM;
    const int n0 = blockIdx.x * BN;

    const int lr = lane >> 3;       // local row within 8-row DMA chunk
    const int gs = lane & 7;        // granule slot within row

    if (MODE == 0 && tid < 8) centS[tid] = cent[tid];

    // NT B tile DMA: [n-row][32k]; granule slot g holds data granule
    // g^((row>>3)&7) via pre-swizzled SOURCE address (dest linear).
    auto stageNT = [&](float* dst, const float* src, int kt) {
#pragma unroll
        for (int q = 0; q < 4; ++q) {
            const int rb  = wid * 32 + q * 8;
            const int key = (rb >> 3) & 7;                 // wave-uniform
            const float* gp = src + (size_t)(n0 + rb + lr) * DK
                                  + kt * BKT + ((gs ^ key) << 2);
            gll16(gp, dst + rb * BKT);
        }
    };
    // NN B tile DMA (mode 1): Bs[kk][n], linear.
    auto stageNN = [&](float* dst, const float* src, int kt) {
#pragma unroll
        for (int q = 0; q < 4; ++q) {
            const int r2 = (wid * 4 + q) * 2;
            const float* gp = src + (size_t)(kt * BKT + r2 + (lane >> 5)) * DK
                                  + n0 + ((lane & 31) << 2);
            gll16(gp, dst + r2 * BN);
        }
    };

    const float* aRow = A + (size_t)(m0 + ty8 * 8) * DK;
    const int bkr = tx8 & 7;   // NT read-side XOR key

    float chn[8][8];
#pragma unroll
    for (int i = 0; i < 8; ++i)
#pragma unroll
        for (int j = 0; j < 8; ++j) chn[i][j] = 0.0f;

    // ---- prologue: stage B tile 0 ----
    if (MODE == 1) stageNN(Bs[0], W, 0); else stageNT(Bs[0], W, 0);
    __syncthreads();                      // drains DMA; centS visible

    int cur = 0;
    for (int kt = 0; kt < NKT; ++kt) {
        if (kt + 1 < NKT) {               // issue next B tile before compute
            if (MODE == 1) stageNN(Bs[cur ^ 1], W, kt + 1);
            else           stageNT(Bs[cur ^ 1], W, kt + 1);
        }

        const float4* Bs4 = (const float4*)Bs[cur];
#pragma unroll
        for (int c = 0; c < 8; ++c) {
            if constexpr (MODE != 1) {
                float4 b4[8];             // resident operand (32 VGPR)
#pragma unroll
                for (int j = 0; j < 8; ++j)
                    b4[j] = Bs4[(tx8 * 8 + j) * 8 + (c ^ bkr)];
#pragma unroll
                for (int i = 0; i < 8; ++i) {
                    const float4 a =      // A streamed: one float4 transient
                        *(const float4*)(aRow + (size_t)i * DK + kt * BKT + c * 4);
#pragma unroll
                    for (int e = 0; e < 4; ++e) {
                        const float ae = ((const float*)&a)[e];
#pragma unroll
                        for (int j = 0; j < 8; ++j)
                            chn[i][j] = fmaf(ae, ((const float*)&b4[j])[e],
                                             chn[i][j]);
                    }
                }
            } else {
                float4 a4[8];             // resident operand (32 VGPR)
#pragma unroll
                for (int i = 0; i < 8; ++i)
                    a4[i] = *(const float4*)(aRow + (size_t)i * DK + kt * BKT + c * 4);
#pragma unroll
                for (int e = 0; e < 4; ++e) {   // B streamed: 8 floats per e
                    const float4 b0 = *(const float4*)&Bs[cur][(c * 4 + e) * BN + tx8 * 8];
                    const float4 b1 = *(const float4*)&Bs[cur][(c * 4 + e) * BN + tx8 * 8 + 4];
                    const float b[8] = {b0.x, b0.y, b0.z, b0.w, b1.x, b1.y, b1.z, b1.w};
#pragma unroll
                    for (int i = 0; i < 8; ++i) {
                        const float ae = ((const float*)&a4[i])[e];
#pragma unroll
                        for (int j = 0; j < 8; ++j)
                            chn[i][j] = fmaf(ae, b[j], chn[i][j]);
                    }
                }
            }
        }

        // ---- KC=512 panel flush: park P0 in out, restart chain ----
        if (kt == FLUSH_KT) {
#pragma unroll
            for (int i = 0; i < 8; ++i) {
                const int row = m0 + ty8 * 8 + i;
#pragma unroll
                for (int jq = 0; jq < 2; ++jq) {
                    float4 v;
                    v.x = chn[i][jq * 4 + 0];
                    v.y = chn[i][jq * 4 + 1];
                    v.z = chn[i][jq * 4 + 2];
                    v.w = chn[i][jq * 4 + 3];
                    *(float4*)&out[(size_t)row * DK + n0 + tx8 * 8 + jq * 4] = v;
                    chn[i][jq * 4 + 0] = 0.0f;
                    chn[i][jq * 4 + 1] = 0.0f;
                    chn[i][jq * 4 + 2] = 0.0f;
                    chn[i][jq * 4 + 3] = 0.0f;
                }
            }
        }

        __syncthreads();     // drains DMA; next B buffer ready
        cur ^= 1;
    }

    // ---- epilogue: tot = P0(from out) + P1(chn), in order ----
    if constexpr (MODE == 0) {
        float bb[7];
#pragma unroll
        for (int t = 0; t < 7; ++t) bb[t] = bnd[t];
#pragma unroll
        for (int i = 0; i < 8; ++i) {
            const int row = m0 + ty8 * 8 + i;
#pragma unroll
            for (int jq = 0; jq < 2; ++jq) {
                const int col = n0 + tx8 * 8 + jq * 4;
                const float4 p = *(const float4*)&out[(size_t)row * DK + col];
                float4 v, yv;
#pragma unroll
                for (int e = 0; e < 4; ++e) {
                    const float yf = ((const float*)&p)[e] + chn[i][jq * 4 + e];
                    int id = 0;
#pragma unroll
                    for (int t = 0; t < 7; ++t) id += (yf > bb[t]) ? 1 : 0;
                    ((float*)&v)[e]  = (float)id;
                    ((float*)&yv)[e] = centS[id];
                }
                *(float4*)&out[(size_t)row * DK + col]  = v;
                *(float4*)&yout[(size_t)row * DK + col] = yv;
            }
        }
    } else if constexpr (MODE == 1) {
#pragma unroll
        for (int i = 0; i < 8; ++i) {
            const int row = m0 + ty8 * 8 + i;
#pragma unroll
            for (int jq = 0; jq < 2; ++jq) {
                const int col = n0 + tx8 * 8 + jq * 4;
                const float4 p  = *(const float4*)&out[(size_t)row * DK + col];
                const float4 xv = *(const float4*)&X[(size_t)row * DK + col];
                float4 v;
                v.x = xv.x - (p.x + chn[i][jq * 4 + 0]);
                v.y = xv.y - (p.y + chn[i][jq * 4 + 1]);
                v.z = xv.z - (p.z + chn[i][jq * 4 + 2]);
                v.w = xv.w - (p.w + chn[i][jq * 4 + 3]);
                *(float4*)&out[(size_t)row * DK + col] = v;
            }
        }
    } else {
#pragma unroll
        for (int i = 0; i < 8; ++i) {
            const int row = m0 + ty8 * 8 + i;
#pragma unroll
            for (int jq = 0; jq < 2; ++jq) {
                const int col = n0 + tx8 * 8 + jq * 4;
                const float4 p = *(const float4*)&out[(size_t)row * DK + col];
                float4 v;
#pragma unroll
                for (int e = 0; e < 4; ++e)
                    ((float*)&v)[e] =
                        ((((const float*)&p)[e] + chn[i][jq * 4 + e]) >= 0.0f)
                            ? 1.0f : -1.0f;
                *(float4*)&out[(size_t)row * DK + col] = v;
            }
        }
    }
}

// Fallback mode-1 (LUT-based, r13-verbatim) for the small-ws path.
__global__ __launch_bounds__(256)
void gk1_lut(const float* __restrict__ IDXF,
             const float* __restrict__ W,
             const float* __restrict__ X,
             const float* __restrict__ cent,
             float* __restrict__ out)
{
    __shared__ float As[2][BM * BKT];
    __shared__ float Bs[2][BN * BKT];
    __shared__ float centS[8];

    const int tid  = threadIdx.x;
    const int lane = tid & 63;
    const int wid  = tid >> 6;
    const int tx8 = tid & 15, ty8 = tid >> 4;
    const int m0 = blockIdx.y * BM;
    const int n0 = blockIdx.x * BN;

    const int arow = tid >> 1;
    const int ah   = (tid & 1) * 4;
    const int akey = (arow >> 3) & 7;
    float4 pidx[4];

    if (tid < 8) centS[tid] = cent[tid];

    auto stageNN = [&](float* dst, const float* src, int kt) {
#pragma unroll
        for (int q = 0; q < 4; ++q) {
            const int r2 = (wid * 4 + q) * 2;
            const float* gp = src + (size_t)(kt * BKT + r2 + (lane >> 5)) * DK
                                  + n0 + ((lane & 31) << 2);
            gll16(gp, dst + r2 * BN);
        }
    };
    auto loadIdx = [&](int kt) {
#pragma unroll
        for (int g = 0; g < 4; ++g)
            pidx[g] = *(const float4*)&IDXF[(size_t)(m0 + arow) * DK + kt * BKT + (ah + g) * 4];
    };
    auto writeA = [&](float* dst) {
#pragma unroll
        for (int g = 0; g < 4; ++g) {
            float4 v;
            v.x = centS[(int)pidx[g].x];
            v.y = centS[(int)pidx[g].y];
            v.z = centS[(int)pidx[g].z];
            v.w = centS[(int)pidx[g].w];
            *(float4*)&dst[arow * BKT + (((ah + g) ^ akey) << 2)] = v;
        }
    };

    float chn[8][8];
#pragma unroll
    for (int i = 0; i < 8; ++i)
#pragma unroll
        for (int j = 0; j < 8; ++j) chn[i][j] = 0.0f;

    const int akr = ty8 & 7;

    loadIdx(0); stageNN(Bs[0], W, 0);
    __syncthreads();
    writeA(As[0]); __syncthreads();

    int cur = 0;
    for (int kt = 0; kt < NKT; ++kt) {
        if (kt + 1 < NKT) { loadIdx(kt + 1); stageNN(Bs[cur ^ 1], W, kt + 1); }

        const float4* As4 = (const float4*)As[cur];
#pragma unroll
        for (int c = 0; c < 8; ++c) {
            float4 a4[8];
#pragma unroll
            for (int i = 0; i < 8; ++i)
                a4[i] = As4[(ty8 * 8 + i) * 8 + (c ^ akr)];
#pragma unroll
            for (int e = 0; e < 4; ++e) {
                const float4 b0 = *(const float4*)&Bs[cur][(c * 4 + e) * BN + tx8 * 8];
                const float4 b1 = *(const float4*)&Bs[cur][(c * 4 + e) * BN + tx8 * 8 + 4];
                const float b[8] = {b0.x, b0.y, b0.z, b0.w, b1.x, b1.y, b1.z, b1.w};
#pragma unroll
                for (int i = 0; i < 8; ++i) {
                    const float ae = ((const float*)&a4[i])[e];
#pragma unroll
                    for (int j = 0; j < 8; ++j)
                        chn[i][j] = fmaf(ae, b[j], chn[i][j]);
                }
            }
        }

        if (kt == FLUSH_KT) {
#pragma unroll
            for (int i = 0; i < 8; ++i) {
                const int row = m0 + ty8 * 8 + i;
#pragma unroll
                for (int jq = 0; jq < 2; ++jq) {
                    float4 v;
                    v.x = chn[i][jq * 4 + 0];
                    v.y = chn[i][jq * 4 + 1];
                    v.z = chn[i][jq * 4 + 2];
                    v.w = chn[i][jq * 4 + 3];
                    *(float4*)&out[(size_t)row * DK + n0 + tx8 * 8 + jq * 4] = v;
                    chn[i][jq * 4 + 0] = 0.0f;
                    chn[i][jq * 4 + 1] = 0.0f;
                    chn[i][jq * 4 + 2] = 0.0f;
                    chn[i][jq * 4 + 3] = 0.0f;
                }
            }
        }

        if (kt + 1 < NKT) writeA(As[cur ^ 1]);
        __syncthreads();
        cur ^= 1;
    }

#pragma unroll
    for (int i = 0; i < 8; ++i) {
        const int row = m0 + ty8 * 8 + i;
#pragma unroll
        for (int jq = 0; jq < 2; ++jq) {
            const int col = n0 + tx8 * 8 + jq * 4;
            const float4 p  = *(const float4*)&out[(size_t)row * DK + col];
            const float4 xv = *(const float4*)&X[(size_t)row * DK + col];
            float4 v;
            v.x = xv.x - (p.x + chn[i][jq * 4 + 0]);
            v.y = xv.y - (p.y + chn[i][jq * 4 + 1]);
            v.z = xv.z - (p.z + chn[i][jq * 4 + 2]);
            v.w = xv.w - (p.w + chn[i][jq * 4 + 3]);
            *(float4*)&out[(size_t)row * DK + col] = v;
        }
    }
}

__global__ __launch_bounds__(256)
void norm_k(const float* __restrict__ resid, float* __restrict__ outn)
{
    const int lane = threadIdx.x & 63;
    const int row  = blockIdx.x * 4 + (threadIdx.x >> 6);
    const float* r = &resid[(size_t)row * DK];
    double s = 0.0;
    for (int i = lane; i < DK; i += 64) {
        const double v = (double)r[i];
        s += v * v;
    }
#pragma unroll
    for (int off = 32; off > 0; off >>= 1)
        s += __shfl_xor(s, off, 64);
    if (lane == 0) outn[row] = (float)sqrt(s);
}

__global__ __launch_bounds__(256)
void stage2_band(const float* __restrict__ RS,
                 const float* __restrict__ Sm,
                 float* __restrict__ out_sign,
                 float* __restrict__ out_norm)
{
    __shared__ float Rs[16][DK + 1];
    __shared__ float Bsh[16][64];

    const int tid = threadIdx.x;
    const int m0  = blockIdx.x * 16;

    for (int c = tid; c < 16 * 256; c += 256) {
        const int row = c >> 8, q = c & 255;
        const float4 v = *(const float4*)&RS[(size_t)(m0 + row) * DK + q * 4];
        Rs[row][q * 4 + 0] = v.x;
        Rs[row][q * 4 + 1] = v.y;
        Rs[row][q * 4 + 2] = v.z;
        Rs[row][q * 4 + 3] = v.w;
    }
    __syncthreads();

    {
        const int row = tid >> 4, sub = tid & 15;
        double s = 0.0;
        for (int c = sub; c < DK; c += 16) {
            const double v = (double)Rs[row][c];
            s += v * v;
        }
        s += __shfl_xor(s, 1, 16);
        s += __shfl_xor(s, 2, 16);
        s += __shfl_xor(s, 4, 16);
        s += __shfl_xor(s, 8, 16);
        if (sub == 0) out_norm[m0 + row] = (float)sqrt(s);
    }

    const int tx = tid & 15, ty = tid >> 4;
    const int srow = tid >> 2, s4 = tid & 3;

    for (int nt = 0; nt < 16; ++nt) {
        const int n0 = nt * 64;
        float chn[4] = {0.f, 0.f, 0.f, 0.f}, tot[4] = {0.f, 0.f, 0.f, 0.f};

        for (int kt = 0; kt < 64; ++kt) {
            const int k0 = kt * 16;
            __syncthreads();
            const float4 w = *(const float4*)&Sm[(size_t)(n0 + srow) * DK + k0 + s4 * 4];
            Bsh[s4 * 4 + 0][srow] = w.x;
            Bsh[s4 * 4 + 1][srow] = w.y;
            Bsh[s4 * 4 + 2][srow] = w.z;
            Bsh[s4 * 4 + 3][srow] = w.w;
            __syncthreads();
#pragma unroll
            for (int kk = 0; kk < 16; ++kk) {
                const float a = Rs[ty][k0 + kk];
#pragma unroll
                for (int j = 0; j < 4; ++j)
                    chn[j] = fmaf(a, Bsh[kk][tx * 4 + j], chn[j]);
            }
            if (kt == 31) {
#pragma unroll
                for (int j = 0; j < 4; ++j) { tot[j] += chn[j]; chn[j] = 0.0f; }
            }
        }
#pragma unroll
        for (int j = 0; j < 4; ++j) tot[j] += chn[j];
#pragma unroll
        for (int j = 0; j < 4; ++j)
            out_sign[(size_t)(m0 + ty) * DK + n0 + tx * 4 + j] =
                (tot[j] >= 0.0f) ? 1.0f : -1.0f;
    }
}

extern "C" void kernel_launch(void* const* d_in, const int* in_sizes, int n_in,
                              void* d_out, int out_size, void* d_ws, size_t ws_size,
                              hipStream_t stream)
{
    const float* x    = (const float*)d_in[0];
    const float* Pi   = (const float*)d_in[1];
    const float* S    = (const float*)d_in[2];
    const float* cent = (const float*)d_in[3];
    const float* bnd  = (const float*)d_in[4];

    float* out_idx  = (float*)d_out;
    float* out_sign = out_idx + (size_t)NB * DK;
    float* out_norm = out_idx + 2 * (size_t)NB * DK;

    const dim3 grid(DK / BN, NB / BM);      // (8, 256)
    const size_t needF32 = (size_t)NB * DK * sizeof(float);   // 134 MB

    // mode 0: idx -> out_idx, yhat -> out_sign (overwritten later by signs)
    gk<0><<<grid, 256, 0, stream>>>(x, Pi, (const float*)nullptr, cent, bnd,
                                    out_idx, out_sign);

    if (ws_size >= needF32) {
        float* resid = (float*)d_ws;
        gk<1><<<grid, 256, 0, stream>>>(out_sign /*A=yhat*/, Pi, x, cent, bnd,
                                        resid, (float*)nullptr);
        gk<2><<<grid, 256, 0, stream>>>(resid, S, (const float*)nullptr, cent, bnd,
                                        out_sign, (float*)nullptr);
        norm_k<<<NB / 4, 256, 0, stream>>>(resid, out_norm);
    } else {
        gk1_lut<<<grid, 256, 0, stream>>>(out_idx, Pi, x, cent, out_sign);
        stage2_band<<<NB / 16, 256, 0, stream>>>(out_sign, S, out_sign, out_norm);
    }
}

// Round 16
// 3641.607 us; speedup vs baseline: 4.7727x; 4.7727x over previous
//
#include <hip/hip_runtime.h>

#define DK 1024
#define NB 32768
#define BM 128
#define BN 64
#define BKT 32
#define NKT (DK / BKT)     // 32 k-tiles
#define FLUSH_KT 15        // KC=512 panel boundary (after kt 15)

typedef const __attribute__((address_space(1))) void GAS;
typedef __attribute__((address_space(3))) void LAS;

__device__ __forceinline__ void gll16(const void* g, void* l) {
    __builtin_amdgcn_global_load_lds((GAS*)g, (LAS*)l, 16, 0, 0);
}

// Reference model (probes r4-r8, verified r9-r15): np ref = f32 sgemm, KC=512
// K-panels; per element ascending-k single-accumulator f32 FMA chain per
// panel; panel sums added in order (P0 + P1). DO NOT reorder the chain.
// P0 parked in `out` at kt==FLUSH_KT, re-read in epilogue (same thread).
//
// r16: occupancy via honest VGPR diet (NO forcing attributes — r11/r15 both
// collapsed to 64 VGPR + full spill). Thread tile 8x4 (32 acc regs), block
// tile 128x64, live set ~100 regs -> 4 waves/SIMD naturally.
// MODE 0: y = x @ Pi^T (NT B) -> idx to out, yhat=cent[idx] to yout
// MODE 1: xhat = yhat @ Pi (NN B) -> resid = x - xhat to out
// MODE 2: p = resid @ S^T (NT B) -> sign to out
template<int MODE>
__global__ __launch_bounds__(256)
void gk(const float* __restrict__ A,
        const float* __restrict__ W,
        const float* __restrict__ X,
        const float* __restrict__ cent,
        const float* __restrict__ bnd,
        float* __restrict__ out,
        float* __restrict__ yout)
{
    __shared__ float Bs[2][BN * BKT];   // 2 x 8 KB
    __shared__ float centS[8];

    const int tid  = threadIdx.x;
    const int lane = tid & 63;
    const int wid  = tid >> 6;
    const int tx = tid & 15, ty = tid >> 4;   // thread tile: rows ty*8+0..7, cols tx*4+0..3
    const int m0 = blockIdx.y * BM;
    const int n0 = blockIdx.x * BN;

    const int lr = lane >> 3;       // row-within-8 for NT DMA
    const int gs = lane & 7;        // granule slot

    if (MODE == 0 && tid < 8) centS[tid] = cent[tid];

    // NT B tile DMA: [n-row][32k]; slot g holds data granule g^((row>>3)&7)
    // via pre-swizzled SOURCE (dest linear). 8 instrs/block (2 per wave).
    auto stageNT = [&](float* dst, const float* src, int kt) {
#pragma unroll
        for (int q = 0; q < 2; ++q) {
            const int rb  = wid * 16 + q * 8;
            const int key = (rb >> 3) & 7;                 // wave-uniform
            const float* gp = src + (size_t)(n0 + rb + lr) * DK
                                  + kt * BKT + ((gs ^ key) << 2);
            gll16(gp, dst + rb * BKT);
        }
    };
    // NN B tile DMA (mode 1): Bs[kk][64n], linear; 4 kk-rows per instr.
    auto stageNN = [&](float* dst, const float* src, int kt) {
#pragma unroll
        for (int q = 0; q < 2; ++q) {
            const int p = wid * 2 + q;
            const float* gp = src + (size_t)(kt * BKT + p * 4 + (lane >> 4)) * DK
                                  + n0 + ((lane & 15) << 2);
            gll16(gp, dst + p * 256);
        }
    };

    const float* aRow = A + (size_t)(m0 + ty * 8) * DK;
    const int bkr = (tx >> 1) & 7;  // NT read key: rows tx*4..tx*4+3 share (row>>3)&7

    float chn[8][4];
#pragma unroll
    for (int i = 0; i < 8; ++i)
#pragma unroll
        for (int j = 0; j < 4; ++j) chn[i][j] = 0.0f;

    // ---- prologue ----
    if (MODE == 1) stageNN(Bs[0], W, 0); else stageNT(Bs[0], W, 0);
    __syncthreads();                      // drains DMA; centS visible

    int cur = 0;
    for (int kt = 0; kt < NKT; ++kt) {
        if (kt + 1 < NKT) {               // issue next B tile before compute
            if (MODE == 1) stageNN(Bs[cur ^ 1], W, kt + 1);
            else           stageNT(Bs[cur ^ 1], W, kt + 1);
        }

        const float4* Bs4 = (const float4*)Bs[cur];
#pragma unroll
        for (int c = 0; c < 8; ++c) {
            float4 b4[4];                 // resident operand (16 VGPR)
            if constexpr (MODE != 1) {
#pragma unroll
                for (int j = 0; j < 4; ++j)
                    b4[j] = Bs4[(tx * 4 + j) * 8 + (c ^ bkr)];   // [j] -> e-vector
            } else {
#pragma unroll
                for (int e = 0; e < 4; ++e)
                    b4[e] = *(const float4*)&Bs[cur][(c * 4 + e) * BN + tx * 4]; // [e] -> j-vector
            }
#pragma unroll
            for (int g = 0; g < 2; ++g) { // rows in 2 groups of 4 (keeps a4 small)
                float4 a4[4];             // transient (16 VGPR)
#pragma unroll
                for (int i = 0; i < 4; ++i)
                    a4[i] = *(const float4*)(aRow + (size_t)(g * 4 + i) * DK
                                             + kt * BKT + c * 4);
#pragma unroll
                for (int e = 0; e < 4; ++e)       // ascending k within granule
#pragma unroll
                    for (int i = 0; i < 4; ++i) {
                        const float ae = ((const float*)&a4[i])[e];
#pragma unroll
                        for (int j = 0; j < 4; ++j) {
                            const float be = (MODE != 1)
                                ? ((const float*)&b4[j])[e]
                                : ((const float*)&b4[e])[j];
                            chn[g * 4 + i][j] = fmaf(ae, be, chn[g * 4 + i][j]);
                        }
                    }
            }
        }

        // ---- KC=512 panel flush: park P0 in out, restart chain ----
        if (kt == FLUSH_KT) {
#pragma unroll
            for (int i = 0; i < 8; ++i) {
                const int row = m0 + ty * 8 + i;
                float4 v;
                v.x = chn[i][0]; v.y = chn[i][1]; v.z = chn[i][2]; v.w = chn[i][3];
                *(float4*)&out[(size_t)row * DK + n0 + tx * 4] = v;
                chn[i][0] = 0.0f; chn[i][1] = 0.0f; chn[i][2] = 0.0f; chn[i][3] = 0.0f;
            }
        }

        __syncthreads();     // drains DMA; next B buffer ready
        cur ^= 1;
    }

    // ---- epilogue: tot = P0(from out) + P1(chn), in order ----
    if constexpr (MODE == 0) {
        float bb[7];
#pragma unroll
        for (int t = 0; t < 7; ++t) bb[t] = bnd[t];
#pragma unroll
        for (int i = 0; i < 8; ++i) {
            const int row = m0 + ty * 8 + i;
            const int col = n0 + tx * 4;
            const float4 p = *(const float4*)&out[(size_t)row * DK + col];
            float4 v, yv;
#pragma unroll
            for (int e = 0; e < 4; ++e) {
                const float yf = ((const float*)&p)[e] + chn[i][e];
                int id = 0;
#pragma unroll
                for (int t = 0; t < 7; ++t) id += (yf > bb[t]) ? 1 : 0;
                ((float*)&v)[e]  = (float)id;
                ((float*)&yv)[e] = centS[id];
            }
            *(float4*)&out[(size_t)row * DK + col]  = v;
            *(float4*)&yout[(size_t)row * DK + col] = yv;
        }
    } else if constexpr (MODE == 1) {
#pragma unroll
        for (int i = 0; i < 8; ++i) {
            const int row = m0 + ty * 8 + i;
            const int col = n0 + tx * 4;
            const float4 p  = *(const float4*)&out[(size_t)row * DK + col];
            const float4 xv = *(const float4*)&X[(size_t)row * DK + col];
            float4 v;
            v.x = xv.x - (p.x + chn[i][0]);
            v.y = xv.y - (p.y + chn[i][1]);
            v.z = xv.z - (p.z + chn[i][2]);
            v.w = xv.w - (p.w + chn[i][3]);
            *(float4*)&out[(size_t)row * DK + col] = v;
        }
    } else {
#pragma unroll
        for (int i = 0; i < 8; ++i) {
            const int row = m0 + ty * 8 + i;
            const int col = n0 + tx * 4;
            const float4 p = *(const float4*)&out[(size_t)row * DK + col];
            float4 v;
#pragma unroll
            for (int e = 0; e < 4; ++e)
                ((float*)&v)[e] =
                    ((((const float*)&p)[e] + chn[i][e]) >= 0.0f) ? 1.0f : -1.0f;
            *(float4*)&out[(size_t)row * DK + col] = v;
        }
    }
}

// Fallback mode-1 (LUT-based, r13 structure, 128x128 tile) for small-ws path.
__global__ __launch_bounds__(256)
void gk1_lut(const float* __restrict__ IDXF,
             const float* __restrict__ W,
             const float* __restrict__ X,
             const float* __restrict__ cent,
             float* __restrict__ out)
{
    __shared__ float As[2][128 * 32];
    __shared__ float Bs[2][128 * 32];
    __shared__ float centS[8];

    const int tid  = threadIdx.x;
    const int lane = tid & 63;
    const int wid  = tid >> 6;
    const int tx8 = tid & 15, ty8 = tid >> 4;
    const int m0 = blockIdx.y * 128;
    const int n0 = blockIdx.x * 128;

    const int arow = tid >> 1;
    const int ah   = (tid & 1) * 4;
    const int akey = (arow >> 3) & 7;
    float4 pidx[4];

    if (tid < 8) centS[tid] = cent[tid];

    auto stageNN = [&](float* dst, const float* src, int kt) {
#pragma unroll
        for (int q = 0; q < 4; ++q) {
            const int r2 = (wid * 4 + q) * 2;
            const float* gp = src + (size_t)(kt * 32 + r2 + (lane >> 5)) * DK
                                  + n0 + ((lane & 31) << 2);
            gll16(gp, dst + r2 * 128);
        }
    };
    auto loadIdx = [&](int kt) {
#pragma unroll
        for (int g = 0; g < 4; ++g)
            pidx[g] = *(const float4*)&IDXF[(size_t)(m0 + arow) * DK + kt * 32 + (ah + g) * 4];
    };
    auto writeA = [&](float* dst) {
#pragma unroll
        for (int g = 0; g < 4; ++g) {
            float4 v;
            v.x = centS[(int)pidx[g].x];
            v.y = centS[(int)pidx[g].y];
            v.z = centS[(int)pidx[g].z];
            v.w = centS[(int)pidx[g].w];
            *(float4*)&dst[arow * 32 + (((ah + g) ^ akey) << 2)] = v;
        }
    };

    float chn[8][8];
#pragma unroll
    for (int i = 0; i < 8; ++i)
#pragma unroll
        for (int j = 0; j < 8; ++j) chn[i][j] = 0.0f;

    const int akr = ty8 & 7;

    loadIdx(0); stageNN(Bs[0], W, 0);
    __syncthreads();
    writeA(As[0]); __syncthreads();

    int cur = 0;
    for (int kt = 0; kt < NKT; ++kt) {
        if (kt + 1 < NKT) { loadIdx(kt + 1); stageNN(Bs[cur ^ 1], W, kt + 1); }

        const float4* As4 = (const float4*)As[cur];
#pragma unroll
        for (int c = 0; c < 8; ++c) {
            float4 a4[8];
#pragma unroll
            for (int i = 0; i < 8; ++i)
                a4[i] = As4[(ty8 * 8 + i) * 8 + (c ^ akr)];
#pragma unroll
            for (int e = 0; e < 4; ++e) {
                const float4 b0 = *(const float4*)&Bs[cur][(c * 4 + e) * 128 + tx8 * 8];
                const float4 b1 = *(const float4*)&Bs[cur][(c * 4 + e) * 128 + tx8 * 8 + 4];
                const float b[8] = {b0.x, b0.y, b0.z, b0.w, b1.x, b1.y, b1.z, b1.w};
#pragma unroll
                for (int i = 0; i < 8; ++i) {
                    const float ae = ((const float*)&a4[i])[e];
#pragma unroll
                    for (int j = 0; j < 8; ++j)
                        chn[i][j] = fmaf(ae, b[j], chn[i][j]);
                }
            }
        }

        if (kt == FLUSH_KT) {
#pragma unroll
            for (int i = 0; i < 8; ++i) {
                const int row = m0 + ty8 * 8 + i;
#pragma unroll
                for (int jq = 0; jq < 2; ++jq) {
                    float4 v;
                    v.x = chn[i][jq * 4 + 0];
                    v.y = chn[i][jq * 4 + 1];
                    v.z = chn[i][jq * 4 + 2];
                    v.w = chn[i][jq * 4 + 3];
                    *(float4*)&out[(size_t)row * DK + n0 + tx8 * 8 + jq * 4] = v;
                    chn[i][jq * 4 + 0] = 0.0f;
                    chn[i][jq * 4 + 1] = 0.0f;
                    chn[i][jq * 4 + 2] = 0.0f;
                    chn[i][jq * 4 + 3] = 0.0f;
                }
            }
        }

        if (kt + 1 < NKT) writeA(As[cur ^ 1]);
        __syncthreads();
        cur ^= 1;
    }

#pragma unroll
    for (int i = 0; i < 8; ++i) {
        const int row = m0 + ty8 * 8 + i;
#pragma unroll
        for (int jq = 0; jq < 2; ++jq) {
            const int col = n0 + tx8 * 8 + jq * 4;
            const float4 p  = *(const float4*)&out[(size_t)row * DK + col];
            const float4 xv = *(const float4*)&X[(size_t)row * DK + col];
            float4 v;
            v.x = xv.x - (p.x + chn[i][jq * 4 + 0]);
            v.y = xv.y - (p.y + chn[i][jq * 4 + 1]);
            v.z = xv.z - (p.z + chn[i][jq * 4 + 2]);
            v.w = xv.w - (p.w + chn[i][jq * 4 + 3]);
            *(float4*)&out[(size_t)row * DK + col] = v;
        }
    }
}

__global__ __launch_bounds__(256)
void norm_k(const float* __restrict__ resid, float* __restrict__ outn)
{
    const int lane = threadIdx.x & 63;
    const int row  = blockIdx.x * 4 + (threadIdx.x >> 6);
    const float* r = &resid[(size_t)row * DK];
    double s = 0.0;
    for (int i = lane; i < DK; i += 64) {
        const double v = (double)r[i];
        s += v * v;
    }
#pragma unroll
    for (int off = 32; off > 0; off >>= 1)
        s += __shfl_xor(s, off, 64);
    if (lane == 0) outn[row] = (float)sqrt(s);
}

__global__ __launch_bounds__(256)
void stage2_band(const float* __restrict__ RS,
                 const float* __restrict__ Sm,
                 float* __restrict__ out_sign,
                 float* __restrict__ out_norm)
{
    __shared__ float Rs[16][DK + 1];
    __shared__ float Bsh[16][64];

    const int tid = threadIdx.x;
    const int m0  = blockIdx.x * 16;

    for (int c = tid; c < 16 * 256; c += 256) {
        const int row = c >> 8, q = c & 255;
        const float4 v = *(const float4*)&RS[(size_t)(m0 + row) * DK + q * 4];
        Rs[row][q * 4 + 0] = v.x;
        Rs[row][q * 4 + 1] = v.y;
        Rs[row][q * 4 + 2] = v.z;
        Rs[row][q * 4 + 3] = v.w;
    }
    __syncthreads();

    {
        const int row = tid >> 4, sub = tid & 15;
        double s = 0.0;
        for (int c = sub; c < DK; c += 16) {
            const double v = (double)Rs[row][c];
            s += v * v;
        }
        s += __shfl_xor(s, 1, 16);
        s += __shfl_xor(s, 2, 16);
        s += __shfl_xor(s, 4, 16);
        s += __shfl_xor(s, 8, 16);
        if (sub == 0) out_norm[m0 + row] = (float)sqrt(s);
    }

    const int tx = tid & 15, ty = tid >> 4;
    const int srow = tid >> 2, s4 = tid & 3;

    for (int nt = 0; nt < 16; ++nt) {
        const int n0 = nt * 64;
        float chn[4] = {0.f, 0.f, 0.f, 0.f}, tot[4] = {0.f, 0.f, 0.f, 0.f};

        for (int kt = 0; kt < 64; ++kt) {
            const int k0 = kt * 16;
            __syncthreads();
            const float4 w = *(const float4*)&Sm[(size_t)(n0 + srow) * DK + k0 + s4 * 4];
            Bsh[s4 * 4 + 0][srow] = w.x;
            Bsh[s4 * 4 + 1][srow] = w.y;
            Bsh[s4 * 4 + 2][srow] = w.z;
            Bsh[s4 * 4 + 3][srow] = w.w;
            __syncthreads();
#pragma unroll
            for (int kk = 0; kk < 16; ++kk) {
                const float a = Rs[ty][k0 + kk];
#pragma unroll
                for (int j = 0; j < 4; ++j)
                    chn[j] = fmaf(a, Bsh[kk][tx * 4 + j], chn[j]);
            }
            if (kt == 31) {
#pragma unroll
                for (int j = 0; j < 4; ++j) { tot[j] += chn[j]; chn[j] = 0.0f; }
            }
        }
#pragma unroll
        for (int j = 0; j < 4; ++j) tot[j] += chn[j];
#pragma unroll
        for (int j = 0; j < 4; ++j)
            out_sign[(size_t)(m0 + ty) * DK + n0 + tx * 4 + j] =
                (tot[j] >= 0.0f) ? 1.0f : -1.0f;
    }
}

extern "C" void kernel_launch(void* const* d_in, const int* in_sizes, int n_in,
                              void* d_out, int out_size, void* d_ws, size_t ws_size,
                              hipStream_t stream)
{
    const float* x    = (const float*)d_in[0];
    const float* Pi   = (const float*)d_in[1];
    const float* S    = (const float*)d_in[2];
    const float* cent = (const float*)d_in[3];
    const float* bnd  = (const float*)d_in[4];

    float* out_idx  = (float*)d_out;
    float* out_sign = out_idx + (size_t)NB * DK;
    float* out_norm = out_idx + 2 * (size_t)NB * DK;

    const dim3 grid(DK / BN, NB / BM);      // (16, 256)
    const size_t needF32 = (size_t)NB * DK * sizeof(float);   // 134 MB

    // mode 0: idx -> out_idx, yhat -> out_sign (overwritten later by signs)
    gk<0><<<grid, 256, 0, stream>>>(x, Pi, (const float*)nullptr, cent, bnd,
                                    out_idx, out_sign);

    if (ws_size >= needF32) {
        float* resid = (float*)d_ws;
        gk<1><<<grid, 256, 0, stream>>>(out_sign /*A=yhat*/, Pi, x, cent, bnd,
                                        resid, (float*)nullptr);
        gk<2><<<grid, 256, 0, stream>>>(resid, S, (const float*)nullptr, cent, bnd,
                                        out_sign, (float*)nullptr);
        norm_k<<<NB / 4, 256, 0, stream>>>(resid, out_norm);
    } else {
        const dim3 gridF(DK / 128, NB / 128);   // (8, 256)
        gk1_lut<<<gridF, 256, 0, stream>>>(out_idx, Pi, x, cent, out_sign);
        stage2_band<<<NB / 16, 256, 0, stream>>>(out_sign, S, out_sign, out_norm);
    }
}